// Round 1
// baseline (995.532 us; speedup 1.0000x reference)
//
#include <hip/hip_runtime.h>
#include <hip/hip_bf16.h>

// Problem constants
#define Hh 8
#define Bb 1024
#define Ss 7
#define Dd 4096
#define DK 512
#define W3 1536            // 3*DK
#define COLS 1544          // padded LDS row stride (floats): [0..2] unused, col 3 = left zero pad,
                           // data at cols 4..1539, col 1540 = right zero pad
#define Mrows (Bb*Ss)      // 7168

typedef float  f32x4  __attribute__((ext_vector_type(4)));
typedef short  bf16x8 __attribute__((ext_vector_type(8)));

static __device__ __forceinline__ unsigned short f2bf(float f) {
  union { float f; unsigned int u; } v; v.f = f;
  unsigned int u = v.u;
  u += 0x7FFFu + ((u >> 16) & 1u);   // RNE
  return (unsigned short)(u >> 16);
}

static __device__ __forceinline__ void gload_lds16(const void* g, void* l) {
  __builtin_amdgcn_global_load_lds(
      (const __attribute__((address_space(1))) unsigned int*)g,
      (__attribute__((address_space(3))) unsigned int*)l,
      16, 0, 0);
}

// ---------------------------------------------------------------------------
// Kernel 1: per (b,h): neighbor-head sum -> conv(width axis, C=S=7, K=3)
//           -> 7x7 attention -> bf16 A-matrix rows for final GEMM
// ---------------------------------------------------------------------------
__global__ __launch_bounds__(256) void attn_kernel(
    const float* __restrict__ qg, const float* __restrict__ kg, const float* __restrict__ vg,
    const float* __restrict__ cw, const float* __restrict__ cb,
    unsigned short* __restrict__ Abf)
{
  __shared__ float sbuf[Ss][COLS];
  __shared__ float cw_s[147];
  __shared__ float cb_s[7];
  __shared__ float scores_s[49];
  __shared__ float pmat[Ss][Ss];

  const int t  = threadIdx.x;
  const int bh = blockIdx.x;
  const int b  = bh >> 3, h = bh & 7;

  if (t < 147) cw_s[t] = cw[t];
  if (t < 7)   cb_s[t] = cb[t];
  if (t < 7) { sbuf[t][3] = 0.f; sbuf[t][4 + W3] = 0.f; }  // zero pads for conv edges

  // ---- Phase A: load q/k/v head h (+ neighbors h-1,h+1) and sum into LDS ----
  // node layout along width: [key | value | query], each DK wide
  #pragma unroll
  for (int j = 0; j < 11; ++j) {
    int slot = j * 256 + t;               // 2688 float4 slots = 7 rows * 3 regions * 128
    if (slot < 2688) {
      int i   = slot / 384;
      int rem = slot - i * 384;
      int r   = rem >> 7;                 // 0=key,1=value,2=query
      int c   = rem & 127;
      const float* src = (r == 0) ? kg : (r == 1) ? vg : qg;
      long base = (long)(b * Ss + i) * Dd + h * DK + c * 4;
      float4 s = *(const float4*)(src + base);
      if (h > 0) { float4 a = *(const float4*)(src + base - DK); s.x+=a.x; s.y+=a.y; s.z+=a.z; s.w+=a.w; }
      if (h < 7) { float4 a = *(const float4*)(src + base + DK); s.x+=a.x; s.y+=a.y; s.z+=a.z; s.w+=a.w; }
      *(float4*)&sbuf[i][4 + r * DK + c * 4] = s;
    }
  }
  __syncthreads();

  // ---- Phase B: conv along width (channels = 7 sequence positions) ----
  float xo[42];
  #pragma unroll
  for (int j = 0; j < 42; ++j) {
    int slot = j * 256 + t;               // 10752 = 7*1536 outputs
    int o = slot / W3;
    int w = slot - o * W3;
    float acc = cb_s[o];
    #pragma unroll
    for (int i = 0; i < 7; ++i) {
      const float* sp = &sbuf[i][3 + w];  // sp[0]=w-1, sp[1]=w, sp[2]=w+1 (padded)
      const float* wp = &cw_s[(o * 7 + i) * 3];
      acc += wp[0] * sp[0] + wp[1] * sp[1] + wp[2] * sp[2];
    }
    xo[j] = acc;
  }
  __syncthreads();
  #pragma unroll
  for (int j = 0; j < 42; ++j) {
    int slot = j * 256 + t;
    int o = slot / W3;
    int w = slot - o * W3;
    sbuf[o][4 + w] = xo[j];               // x overwrites s_sum
  }
  __syncthreads();

  // ---- Phase D: scores[q][k] = q2 . k2 / sqrt(512), wave-parallel ----
  const int wave = t >> 6, lane = t & 63;
  for (int p = wave; p < 49; p += 4) {
    int qq = p / 7, kk = p % 7;
    const float4 a0 = *(const float4*)&sbuf[qq][4 + 2 * DK + lane * 8];
    const float4 a1 = *(const float4*)&sbuf[qq][4 + 2 * DK + lane * 8 + 4];
    const float4 b0 = *(const float4*)&sbuf[kk][4 + lane * 8];
    const float4 b1 = *(const float4*)&sbuf[kk][4 + lane * 8 + 4];
    float part = a0.x*b0.x + a0.y*b0.y + a0.z*b0.z + a0.w*b0.w
               + a1.x*b1.x + a1.y*b1.y + a1.z*b1.z + a1.w*b1.w;
    #pragma unroll
    for (int off = 32; off; off >>= 1) part += __shfl_xor(part, off);
    if (lane == 0) scores_s[p] = part * 0.044194173824159216f;  // 1/sqrt(512)
  }
  __syncthreads();

  // ---- Phase E: softmax rows ----
  if (t < 7) {
    float row[7], m = -1e30f;
    #pragma unroll
    for (int kk = 0; kk < 7; ++kk) { row[kk] = scores_s[t * 7 + kk]; m = fmaxf(m, row[kk]); }
    float s = 0.f;
    #pragma unroll
    for (int kk = 0; kk < 7; ++kk) { row[kk] = expf(row[kk] - m); s += row[kk]; }
    float inv = 1.0f / s;
    #pragma unroll
    for (int kk = 0; kk < 7; ++kk) pmat[t][kk] = row[kk] * inv;
  }
  __syncthreads();

  // ---- Phase F: atn = P @ v2, write bf16 A rows ----
  #pragma unroll
  for (int qq = 0; qq < 7; ++qq) {
    int d = t * 2;
    float a0 = 0.f, a1 = 0.f;
    #pragma unroll
    for (int kk = 0; kk < 7; ++kk) {
      float pk = pmat[qq][kk];
      a0 += pk * sbuf[kk][4 + DK + d];
      a1 += pk * sbuf[kk][4 + DK + d + 1];
    }
    unsigned int packed = ((unsigned int)f2bf(a1) << 16) | (unsigned int)f2bf(a0);
    *(unsigned int*)&Abf[(long)(b * Ss + qq) * Dd + h * DK + d] = packed;
  }
}

// ---------------------------------------------------------------------------
// Kernel 3: cast w_out (fp32, N x K row-major) -> bf16
// ---------------------------------------------------------------------------
__global__ __launch_bounds__(256) void castw(const float* __restrict__ w, unsigned short* __restrict__ o)
{
  const int total = (Dd * Dd) / 4;        // float4 slots
  for (int s = blockIdx.x * 256 + threadIdx.x; s < total; s += gridDim.x * 256) {
    float4 f = *(const float4*)(w + (long)s * 4);
    ushort4 u;
    u.x = f2bf(f.x); u.y = f2bf(f.y); u.z = f2bf(f.z); u.w = f2bf(f.w);
    *(ushort4*)(o + (long)s * 4) = u;
  }
}

// ---------------------------------------------------------------------------
// Kernel 2: bf16 GEMM  C[m][n] = sum_k A[m][k] * W[n][k] + bias[n]
// m97 structure: 128x128 tile, BK=32, 4 waves, global_load_lds(16B), 16x16x32 MFMA
// ---------------------------------------------------------------------------
#define BM 128
#define BN 128
#define BK 32

__global__ __launch_bounds__(256) void gemm_bt(
    const unsigned short* __restrict__ A, const unsigned short* __restrict__ Bt,
    const float* __restrict__ bias, float* __restrict__ C)
{
  __shared__ unsigned short As[BM * BK];
  __shared__ unsigned short Bs[BN * BK];

  const int t    = threadIdx.x;
  const int m0   = blockIdx.y * BM;
  const int n0   = blockIdx.x * BN;
  const int wave = t >> 6, lane = t & 63;
  const int wm   = (wave >> 1) * 64, wn = (wave & 1) * 64;
  const int lr   = lane & 15, lk = (lane >> 4) * 8;

  const int srow = t >> 2;            // staging: rows 0..63 (j=0), 64..127 (j=1)
  const int scol = (t & 3) * 8;       // bf16 elems

  f32x4 acc[4][4] = {};

  for (int kt = 0; kt < Dd / BK; ++kt) {
    const int k0 = kt * BK;
    #pragma unroll
    for (int j = 0; j < 2; ++j) {
      const int row = j * 64 + srow;
      gload_lds16(A  + (long)(m0 + row) * Dd + k0 + scol, &As[row * BK + scol]);
      gload_lds16(Bt + (long)(n0 + row) * Dd + k0 + scol, &Bs[row * BK + scol]);
    }
    __syncthreads();

    bf16x8 af[4], bfr[4];
    #pragma unroll
    for (int mi = 0; mi < 4; ++mi) af[mi]  = *(const bf16x8*)&As[(wm + mi * 16 + lr) * BK + lk];
    #pragma unroll
    for (int ni = 0; ni < 4; ++ni) bfr[ni] = *(const bf16x8*)&Bs[(wn + ni * 16 + lr) * BK + lk];
    #pragma unroll
    for (int mi = 0; mi < 4; ++mi)
      #pragma unroll
      for (int ni = 0; ni < 4; ++ni)
        acc[mi][ni] = __builtin_amdgcn_mfma_f32_16x16x32_bf16(af[mi], bfr[ni], acc[mi][ni], 0, 0, 0);
    __syncthreads();
  }

  // Epilogue: C/D layout col=lane&15, row=(lane>>4)*4+reg  [measured m89/m91]
  #pragma unroll
  for (int ni = 0; ni < 4; ++ni) {
    const int col = n0 + wn + ni * 16 + lr;
    const float bi = bias[col];
    #pragma unroll
    for (int mi = 0; mi < 4; ++mi) {
      const int rbase = m0 + wm + mi * 16 + (lane >> 4) * 4;
      #pragma unroll
      for (int r = 0; r < 4; ++r)
        C[(long)(rbase + r) * Dd + col] = acc[mi][ni][r] + bi;
    }
  }
}

// ---------------------------------------------------------------------------
extern "C" void kernel_launch(void* const* d_in, const int* in_sizes, int n_in,
                              void* d_out, int out_size, void* d_ws, size_t ws_size,
                              hipStream_t stream) {
  const float* qg = (const float*)d_in[0];
  const float* kg = (const float*)d_in[1];
  const float* vg = (const float*)d_in[2];
  const float* cw = (const float*)d_in[3];
  const float* cb = (const float*)d_in[4];
  const float* wo = (const float*)d_in[5];
  const float* bo = (const float*)d_in[6];
  float* out = (float*)d_out;

  unsigned short* Abf = (unsigned short*)d_ws;                 // 7168*4096 bf16 = 58.7 MB
  unsigned short* Wbf = Abf + (size_t)Mrows * Dd;              // 4096*4096 bf16 = 33.5 MB

  hipLaunchKernelGGL(castw,       dim3(2048),   dim3(256), 0, stream, wo, Wbf);
  hipLaunchKernelGGL(attn_kernel, dim3(Bb * Hh), dim3(256), 0, stream, qg, kg, vg, cw, cb, Abf);
  hipLaunchKernelGGL(gemm_bt,     dim3(Dd / BN, Mrows / BM), dim3(256), 0, stream, Abf, Wbf, bo, out);
}